// Round 5
// baseline (67.718 us; speedup 1.0000x reference)
//
#include <hip/hip_runtime.h>

#define PAD 4

// out[n,c,i,j] = x[n,c, clamp(i+hs[n]-PAD,0,H-1), clamp(j+ws[n]-PAD,0,W-1)]
// N=256, C=12, H=128, W=128, fp32.
//
// Round 5 = Round 4 structure with the COHERENT nontemporal store builtin.
// (Round 4's inline-asm `sc0 sc1 nt` store bypassed L2; the harness's
// memset-zero lines stayed clean in L2 and the readback saw stale zeros.
// __builtin_nontemporal_store emits `nt` only — coherent, proven absmax 0.)
//
//  - 2D grid: blockIdx.y = n -> hs/ws wave-uniform scalar loads, no int div.
//  - Block = 32 rows of one plane; thread owns column quad j0 in rows
//    i0 + {0,8,16,24}; sj/q/s and interior-vs-edge branch are k-invariant.
//  - Interior: 1-2 aligned float4 loads + in-register realign (s uniform).
//    Edge (<=1 col-quad per row): 4 clamped scalar loads.

using vf4 = __attribute__((ext_vector_type(4))) float;

__global__ __launch_bounds__(256) void random_shift_kernel(
    const float* __restrict__ x,
    const int*   __restrict__ h_starts,
    const int*   __restrict__ w_starts,
    float*       __restrict__ out)
{
    constexpr int W = 128, H = 128, C = 12;
    constexpr int PLANE  = H * W;        // 16384 floats
    constexpr int SAMPLE = C * PLANE;    // 196608 floats

    const int n  = blockIdx.y;
    const int ws = w_starts[n] - PAD;    // [-4, 4], wave-uniform
    const int hs = h_starts[n] - PAD;

    const int bx      = blockIdx.x;
    const int c       = bx >> 2;         // plane (4 blocks per plane)
    const int rowbase = (bx & 3) << 5;   // 32-row chunk within plane

    const int t  = threadIdx.x;
    const int r  = t >> 5;               // [0, 8)
    const int j0 = (t & 31) << 2;        // column quad start

    const float* __restrict__ xp = x   + (size_t)n * SAMPLE + (size_t)c * PLANE;
    float*       __restrict__ op = out + (size_t)n * SAMPLE + (size_t)c * PLANE;

    const int i0 = rowbase + r;          // rows i0 + 8k, k = 0..3
    const int sj = j0 + ws;              // k-invariant source column start

    if (sj >= 0 && sj <= W - 4) {
        const int q = sj >> 2;           // [0, 31]
        const int s = sj & 3;            // wave-uniform
        #pragma unroll
        for (int k = 0; k < 4; ++k) {
            int i  = i0 + (k << 3);
            int si = i + hs;
            si = si < 0 ? 0 : (si > H - 1 ? H - 1 : si);
            const vf4* __restrict__ src4 =
                reinterpret_cast<const vf4*>(xp + si * W);
            vf4 A = src4[q];
            vf4 v;
            if (s == 0) {
                v = A;
            } else {
                vf4 B = src4[q + 1];     // q <= 30 when s >= 1
                if (s == 1)      v = (vf4){A.y, A.z, A.w, B.x};
                else if (s == 2) v = (vf4){A.z, A.w, B.x, B.y};
                else             v = (vf4){A.w, B.x, B.y, B.z};
            }
            __builtin_nontemporal_store(v, reinterpret_cast<vf4*>(op + i * W + j0));
        }
    } else {
        #pragma unroll
        for (int k = 0; k < 4; ++k) {
            int i  = i0 + (k << 3);
            int si = i + hs;
            si = si < 0 ? 0 : (si > H - 1 ? H - 1 : si);
            const float* __restrict__ row = xp + si * W;
            vf4 v;
            int j;
            j = sj + 0; j = j < 0 ? 0 : (j > W - 1 ? W - 1 : j); v.x = row[j];
            j = sj + 1; j = j < 0 ? 0 : (j > W - 1 ? W - 1 : j); v.y = row[j];
            j = sj + 2; j = j < 0 ? 0 : (j > W - 1 ? W - 1 : j); v.z = row[j];
            j = sj + 3; j = j < 0 ? 0 : (j > W - 1 ? W - 1 : j); v.w = row[j];
            __builtin_nontemporal_store(v, reinterpret_cast<vf4*>(op + i * W + j0));
        }
    }
}

extern "C" void kernel_launch(void* const* d_in, const int* in_sizes, int n_in,
                              void* d_out, int out_size, void* d_ws, size_t ws_size,
                              hipStream_t stream) {
    const float* x        = (const float*)d_in[0];
    const int*   h_starts = (const int*)d_in[1];
    const int*   w_starts = (const int*)d_in[2];
    float*       out      = (float*)d_out;

    // 12 planes x 4 row-chunks = 48 blocks in x; 256 samples in y.
    dim3 grid(48, 256);
    dim3 block(256);

    random_shift_kernel<<<grid, block, 0, stream>>>(x, h_starts, w_starts, out);
}